// Round 1
// baseline (2103.447 us; speedup 1.0000x reference)
//
#include <hip/hip_runtime.h>

// fp32 I/O. N=32, C=64, T=256, V=50, H=8, hc=8
// plane = T*V = 12800, n-stride = 819200, score K-dim = hc*T = 2048.
// n processed in 4 groups of 8; k tensor staged in d_out (same fp32 size),
// overwritten by K3(g) only after K2(g) consumed it (stream order).
// v-projection folded into o-projection: W2[s,o,a] = sum_c ow[o,s*64+c]*vw[c,a],
// ovb[s,o] = sum_c ow[o,s*64+c]*vb[c]  ->  K3 reads x_kv directly, no v tensor.
//
// R1 change (theory: K3 was SMEM-serialization + I-cache bound):
//   K3 rewritten: x-tile staged to LDS ONCE per block (was re-fetched 8x via
//   wave-uniform s_loads), attn+W2 staged per s, all operand reads are vector
//   LDS reads (b128 broadcasts -> VGPRs, pipelineable) instead of in-order
//   s_loads against the 102-SGPR file. trow-tile=2, wave-pair u-split (24/26
//   merged into one 26-wide code path; dummy lanes read zeroed pad), LDS
//   53.7 KB -> 3 blocks/CU. Cross-pair oacc reduction through reused sx LDS.

// ---------------------------------------------------------------------------
// K0: wT (q/k weight transpose, [c][o]) + W2 + ovb
__global__ void k0_prep(const float* __restrict__ qw, const float* __restrict__ kw,
                        const float* __restrict__ vw, const float* __restrict__ vb,
                        const float* __restrict__ ow,
                        float* __restrict__ wT, float* __restrict__ W2,
                        float* __restrict__ ovb)
{
    int i = threadIdx.x + blockIdx.x * 256;
    if (i < 4096){
        int o = i >> 6, c = i & 63;
        wT[c*64 + o]        = qw[i];
        wT[4096 + c*64 + o] = kw[i];
    } else if (i < 36864){
        int j = i - 4096;
        int s = j >> 12, o = (j >> 6) & 63, a = j & 63;
        float acc = 0.f;
        for (int c = 0; c < 64; ++c)
            acc += ow[o*512 + s*64 + c] * vw[c*64 + a];
        W2[j] = acc;
    } else if (i < 37376){
        int j = i - 36864;
        int s = j >> 6, o = j & 63;
        float acc = 0.f;
        for (int c = 0; c < 64; ++c)
            acc += ow[o*512 + s*64 + c] * vb[c];
        ovb[j] = acc;
    }
}

// ---------------------------------------------------------------------------
// K1: q,k projections for one n-group. Block = (pos-tile, n_rel).
// q -> qchunk (group-relative), k -> d_out (absolute).
__global__ __launch_bounds__(256, 2) void k1_qk(
    const float* __restrict__ xq, const float* __restrict__ xkv,
    const float* __restrict__ wT,
    const float* __restrict__ qb, const float* __restrict__ kb,
    float* __restrict__ qo, float* __restrict__ ko, int n0)
{
    __shared__ float sx[64*256];              // 64 KB, one tensor at a time
    const int nrel = blockIdx.y;
    const int nabs = n0 + nrel;
    const int p0   = blockIdx.x * 256;
    const int tid  = threadIdx.x;
    const size_t abase = (size_t)nabs * 819200;
    const size_t rbase = (size_t)nrel * 819200;

    for (int phase = 0; phase < 2; ++phase){
        const float* src  = phase ? xkv : xq;
        const float* bias = phase ? kb : qb;
        const float* w    = phase ? (wT + 4096) : wT;

        if (phase) __syncthreads();           // readers of prev sx done
        {   // stage 64x256 fp32 tile, float4 coalesced
            const float* g = src + abase + p0;
            #pragma unroll
            for (int j = 0; j < 16; ++j){
                int i4 = tid + j*256;         // 0..4095 float4s
                int c = i4 >> 6, m4 = i4 & 63;
                float4 val = *(const float4*)(g + (size_t)c*12800 + m4*4);
                *(float4*)(&sx[c*256 + m4*4]) = val;
            }
        }
        __syncthreads();

        for (int h = 0; h < 2; ++h){
            const int o0 = h*32;
            float acc[32];
            #pragma unroll
            for (int j = 0; j < 32; ++j) acc[j] = bias[o0+j];
            for (int c = 0; c < 64; ++c){
                float xv = sx[c*256 + tid];
                const float* row = w + c*64 + o0;
                #pragma unroll
                for (int j = 0; j < 32; ++j) acc[j] += row[j] * xv;
            }
            float* dst = phase ? (ko + abase) : (qo + rbase);
            #pragma unroll
            for (int j = 0; j < 32; ++j)
                dst[(size_t)(o0+j)*12800 + p0 + tid] = acc[j];
        }
    }
}

// ---------------------------------------------------------------------------
// K2p: partial scores. Block = n_rel*32 + s*4 + kq (256 blocks/group).
// Each wave sums 128 K-rows; q per-lane, k rows wave-uniform (scalar loads).
__global__ __launch_bounds__(256, 2) void k2_partial(
    const float* __restrict__ qc, const float* __restrict__ kd,
    float* __restrict__ pscore, int n0)
{
    __shared__ float red[4*2500];             // 40 KB
    const int bid  = blockIdx.x;
    const int kq   = bid & 3;
    const int s    = (bid >> 2) & 7;
    const int nrel = bid >> 5;
    const int tid  = threadIdx.x;
    const int wave = __builtin_amdgcn_readfirstlane(tid >> 6);
    const int lane = tid & 63;
    const float* qf = qc + (size_t)nrel * 819200 + (size_t)s * 102400;
    const float* kf = kd + (size_t)(n0 + nrel) * 819200 + (size_t)s * 102400;

    float acc[50];
    #pragma unroll
    for (int w = 0; w < 50; ++w) acc[w] = 0.f;

    if (lane < 50){
        const int r0 = kq*512 + wave*128;
        for (int kk = r0; kk < r0 + 128; kk += 4){
            float qv[4];
            #pragma unroll
            for (int t = 0; t < 4; ++t) qv[t] = qf[(size_t)(kk+t)*50 + lane];
            #pragma unroll
            for (int t = 0; t < 4; ++t){
                const float* kr = kf + (size_t)(kk+t)*50;   // wave-uniform
                #pragma unroll
                for (int w = 0; w < 50; ++w) acc[w] += qv[t] * kr[w];
            }
        }
        #pragma unroll
        for (int w = 0; w < 50; ++w) red[wave*2500 + lane*50 + w] = acc[w];
    }
    __syncthreads();

    for (int i = tid; i < 2500; i += 256)
        pscore[(size_t)bid*2500 + i] = red[i] + red[2500+i] + red[5000+i] + red[7500+i];
}

// ---------------------------------------------------------------------------
// K2f: attn = tanh(score/2048)*alpha + gattn. Block = n_rel*8 + s.
__global__ void k2_final(const float* __restrict__ pscore,
                         const float* __restrict__ alphas, const float* __restrict__ gattn,
                         float* __restrict__ attnc)
{
    const int b = blockIdx.x;
    const int s = b & 7;
    const float inv = 1.0f / 2048.0f;
    const float alpha = alphas[s];
    for (int i = threadIdx.x; i < 2500; i += 256){
        float sum = pscore[(size_t)(b*4+0)*2500 + i] + pscore[(size_t)(b*4+1)*2500 + i]
                  + pscore[(size_t)(b*4+2)*2500 + i] + pscore[(size_t)(b*4+3)*2500 + i];
        attnc[(size_t)b*2500 + i] = tanhf(sum * inv) * alpha + gattn[i];
    }
}

// ---------------------------------------------------------------------------
// K3: out[o,t,w] = ob[o] + sum_s [ sum_u attn[s,u,w] *
//                  (ovb[s,o] + sum_a W2[s,o,a]*x_kv[a,t,u]) ]
// Block = (t-pair tile, n_rel); 256 threads = 4 waves.
// wave wv: ttu = wv>>1 (which of 2 trows), uh = wv&1 (u-half 0..23 / 24..49).
// x tile LDS layout: sx[a][ttu][52] (pad; [50..51] zeroed). attn: att[u][52].
// All operand reads are LDS vector reads (b128 broadcasts); no s_load feeding.
// Both u-halves run one shared 26-wide path: half A's last 2 P-slots are
// dummies (init 0, tail x-read points at the zeroed pad, pv=0 in C-phase).
__global__ __launch_bounds__(256, 3) void k3_out(
    const float* __restrict__ xkv, const float* __restrict__ attnc,
    const float* __restrict__ W2, const float* __restrict__ ovb,
    const float* __restrict__ ob, float* __restrict__ out, int n0)
{
    __shared__ __align__(16) float sx [64*104];   // 26,624 B: [a][2][52]
    __shared__ __align__(16) float sw2[64*65];    // 16,640 B
    __shared__ __align__(16) float att[50*52];    // 10,400 B  (total 53,664 B)

    const int nrel = blockIdx.y;
    const int nabs = n0 + nrel;
    const int tb   = blockIdx.x;                  // trows tb*2 + {0,1}
    const int tid  = threadIdx.x;
    const int o    = tid & 63;
    const int wv   = __builtin_amdgcn_readfirstlane(tid >> 6);
    const int ttu  = wv >> 1;                     // 0..1
    const int uh   = wv & 1;                      // u-half
    const size_t abase = (size_t)nabs * 819200;

    {   // stage x tile once: 64 a-rows x 100 floats (trows tb*2, tb*2+1)
        const float4* xg = (const float4*)(xkv + abase);
        for (int i4 = tid; i4 < 1600; i4 += 256){
            int a = i4 / 25, j = i4 - a*25;
            float4 v = xg[a*3200 + tb*25 + j];
            int r0 = j*4;
            #pragma unroll
            for (int e = 0; e < 4; ++e){
                int r = r0 + e;
                int tt = (r >= 50) ? 1 : 0;
                sx[a*104 + tt*52 + (r - tt*50)] = ((const float*)&v)[e];
            }
        }
        for (int i = tid; i < 128; i += 256){     // zero the pad (dummy reads)
            int a = i >> 1, tt = i & 1;
            sx[a*104 + tt*52 + 50] = 0.f;
            sx[a*104 + tt*52 + 51] = 0.f;
        }
    }

    float oacc[50];
    #pragma unroll
    for (int w = 0; w < 50; ++w) oacc[w] = 0.f;

    const float* sxw  = sx + ttu*52 + uh*24;      // u-window base in x row
    const int    xtail = uh ? 24 : 50;            // f2 tail: real u48,49 or pad
    const int    arow0 = uh*24;                   // att row base

    for (int s = 0; s < 8; ++s){
        __syncthreads();                          // prev P/C done with sw2/att
        for (int j = tid; j < 4096; j += 256)
            sw2[(j >> 6)*65 + (j & 63)] = W2[s*4096 + j];
        {
            const float* asrc = attnc + (size_t)(nrel*8 + s)*2500;
            for (int i = tid; i < 2500; i += 256){
                int u = i / 50;
                att[u*52 + (i - u*50)] = asrc[i];
            }
        }
        __syncthreads();

        // ---- phase P: P[u] = ovb[s,o] + sum_a W2_s[o,a] * x[a,trow,u] ----
        const float pb    = ovb[s*64 + o];
        const float ptail = uh ? pb : 0.f;        // half A's u24,25 are dummies
        float P[26];
        #pragma unroll
        for (int u = 0; u < 26; ++u) P[u] = (u < 24) ? pb : ptail;

        #pragma unroll 4
        for (int a = 0; a < 64; ++a){
            const float w2v = sw2[o*65 + a];      // per-lane, 2-way bank (free)
            const float* x = sxw + a*104;         // wave-uniform broadcasts
            #pragma unroll
            for (int c = 0; c < 6; ++c){
                float4 xv = *(const float4*)(x + c*4);
                P[c*4+0] += w2v * xv.x;
                P[c*4+1] += w2v * xv.y;
                P[c*4+2] += w2v * xv.z;
                P[c*4+3] += w2v * xv.w;
            }
            float2 xt = *(const float2*)(x + xtail);
            P[24] += w2v * xt.x;
            P[25] += w2v * xt.y;
        }

        // ---- phase C: oacc[w] += P[u] * attn[s, arow0+u, w] ----
        #pragma unroll
        for (int u = 0; u < 26; ++u){
            const float pv = P[u];
            const float* ar = att + (arow0 + u)*52;   // wave-uniform broadcast
            #pragma unroll
            for (int c = 0; c < 12; ++c){
                float4 av = *(const float4*)(ar + c*4);
                oacc[c*4+0] += pv * av.x;
                oacc[c*4+1] += pv * av.y;
                oacc[c*4+2] += pv * av.z;
                oacc[c*4+3] += pv * av.w;
            }
            float2 at = *(const float2*)(ar + 48);
            oacc[48] += pv * at.x;
            oacc[49] += pv * at.y;
        }
    }

    // ---- cross-pair (u-half) reduction through reused sx, then store ----
    __syncthreads();                              // sx dead now
    if (uh == 1){
        float* red = sx + (ttu*64 + o)*50;
        #pragma unroll
        for (int w = 0; w < 50; w += 2)
            *(float2*)(red + w) = make_float2(oacc[w], oacc[w+1]);
    }
    __syncthreads();
    if (uh == 0){
        const float bias = ob[o];
        const float* red = sx + (ttu*64 + o)*50;
        const int trg = tb*2 + ttu;
        float* op = out + abase + (size_t)o*12800 + (size_t)trg*50;
        #pragma unroll
        for (int w = 0; w < 50; w += 2){
            float2 rv = *(const float2*)(red + w);
            *(float2*)(op + w) = make_float2(oacc[w]   + rv.x + bias,
                                             oacc[w+1] + rv.y + bias);
        }
    }
}

// ---------------------------------------------------------------------------
extern "C" void kernel_launch(void* const* d_in, const int* in_sizes, int n_in,
                              void* d_out, int out_size, void* d_ws, size_t ws_size,
                              hipStream_t stream)
{
    const float* x_q    = (const float*)d_in[0];
    const float* x_kv   = (const float*)d_in[1];
    const float* q_w    = (const float*)d_in[2];
    const float* q_b    = (const float*)d_in[3];
    const float* k_w    = (const float*)d_in[4];
    const float* k_b    = (const float*)d_in[5];
    const float* v_w    = (const float*)d_in[6];
    const float* v_b    = (const float*)d_in[7];
    const float* o_w    = (const float*)d_in[8];
    const float* o_b    = (const float*)d_in[9];
    const float* alphas = (const float*)d_in[10];
    const float* gattn  = (const float*)d_in[11];
    float* out = (float*)d_out;

    // ws layout (29.6 MB):
    char* ws = (char*)d_ws;
    float* qchunk = (float*)(ws);                  // 26,214,400 B (8n q fp32)
    float* pscore = (float*)(ws + 26214400);       //  2,560,000 B
    float* attnc  = (float*)(ws + 28774400);       //    640,000 B
    float* wT     = (float*)(ws + 29414400);       //     32,768 B
    float* W2     = (float*)(ws + 29447168);       //    131,072 B
    float* ovb    = (float*)(ws + 29578240);       //      2,048 B

    k0_prep<<<146, 256, 0, stream>>>(q_w, k_w, v_w, v_b, o_w, wT, W2, ovb);

    for (int g = 0; g < 4; ++g){
        const int n0 = g * 8;
        k1_qk<<<dim3(50, 8), 256, 0, stream>>>(x_q, x_kv, wT, q_b, k_b,
                                               qchunk, out /*k in d_out*/, n0);
        k2_partial<<<256, 256, 0, stream>>>(qchunk, (const float*)d_out, pscore, n0);
        k2_final<<<64, 256, 0, stream>>>(pscore, alphas, gattn, attnc);
        k3_out<<<dim3(128, 8), 256, 0, stream>>>(x_kv, attnc, W2, ovb, o_b, out, n0);
    }
}

// Round 3
// 1688.043 us; speedup vs baseline: 1.2461x; 1.2461x over previous
//
#include <hip/hip_runtime.h>

// fp32 I/O. N=32, C=64, T=256, V=50, H=8, hc=8
// plane = T*V = 12800, n-stride = 819200, score K-dim = hc*T = 2048.
// n processed in 4 groups of 8; k tensor staged in d_out (same fp32 size),
// overwritten by K3(g) only after K2(g) consumed it (stream order).
// v-projection folded into o-projection: W2T[s,a,o] = sum_c ow[o,s*64+c]*vw[c,a],
// ovb[s,o] = sum_c ow[o,s*64+c]*vb[c]  ->  K3 reads x_kv directly, no v tensor.
//
// R2 change (theory: K3 was LDS-return-BW bound — wave-uniform broadcast reads
// deliver 16 useful B per b128 while occupying the shared per-CU LDS pipe):
//   K3 rewritten as two chained register-tiled GEMMs per (n, 4-trow tile):
//     GEMM1: P[o,u] = ovb + W2_s[o,a] . x[a,trow,u]   (64x64, K=64, per wave)
//     GEMM2: Out[o,w] += P[o,u] . A_s[u,w]            (64x64, K=50, per wave)
//   Per-lane 8x8 outer product: 4 conflict-free lane-fragmented b128 reads per
//   k feed 64 FMAs (LDS:VALU = 1:4, matching 1 LDS unit : 4 SIMDs).
//   P lives in LDS per-wave with XOR swizzle (byte ^= 16*(u>>3)) so the
//   transpose write is conflict-free and the row read stays b128-aligned.
//   K0 emits W2 pre-transposed (W2T[s][a][o]) so per-s staging is linear.
//   LDS 147.9 KB dynamic -> 1 block/CU, 4 waves.
// R3: resubmission of R2 (bench infra failed; kernel never ran). Only change:
//   hipFuncSetAttribute called unconditionally (no static state).

// ---------------------------------------------------------------------------
// K0: wT (q/k weight transpose, [c][o]) + W2T (pre-transposed [s][a][o]) + ovb
__global__ void k0_prep(const float* __restrict__ qw, const float* __restrict__ kw,
                        const float* __restrict__ vw, const float* __restrict__ vb,
                        const float* __restrict__ ow,
                        float* __restrict__ wT, float* __restrict__ W2T,
                        float* __restrict__ ovb)
{
    int i = threadIdx.x + blockIdx.x * 256;
    if (i < 4096){
        int o = i >> 6, c = i & 63;
        wT[c*64 + o]        = qw[i];
        wT[4096 + c*64 + o] = kw[i];
    } else if (i < 36864){
        int j = i - 4096;
        int s = j >> 12, o = (j >> 6) & 63, a = j & 63;
        float acc = 0.f;
        for (int c = 0; c < 64; ++c)
            acc += ow[o*512 + s*64 + c] * vw[c*64 + a];
        W2T[s*4096 + a*64 + o] = acc;            // transposed store
    } else if (i < 37376){
        int j = i - 36864;
        int s = j >> 6, o = j & 63;
        float acc = 0.f;
        for (int c = 0; c < 64; ++c)
            acc += ow[o*512 + s*64 + c] * vb[c];
        ovb[j] = acc;
    }
}

// ---------------------------------------------------------------------------
// K1: q,k projections for one n-group. Block = (pos-tile, n_rel).
// q -> qchunk (group-relative), k -> d_out (absolute).
__global__ __launch_bounds__(256, 2) void k1_qk(
    const float* __restrict__ xq, const float* __restrict__ xkv,
    const float* __restrict__ wT,
    const float* __restrict__ qb, const float* __restrict__ kb,
    float* __restrict__ qo, float* __restrict__ ko, int n0)
{
    __shared__ float sx[64*256];              // 64 KB, one tensor at a time
    const int nrel = blockIdx.y;
    const int nabs = n0 + nrel;
    const int p0   = blockIdx.x * 256;
    const int tid  = threadIdx.x;
    const size_t abase = (size_t)nabs * 819200;
    const size_t rbase = (size_t)nrel * 819200;

    for (int phase = 0; phase < 2; ++phase){
        const float* src  = phase ? xkv : xq;
        const float* bias = phase ? kb : qb;
        const float* w    = phase ? (wT + 4096) : wT;

        if (phase) __syncthreads();           // readers of prev sx done
        {   // stage 64x256 fp32 tile, float4 coalesced
            const float* g = src + abase + p0;
            #pragma unroll
            for (int j = 0; j < 16; ++j){
                int i4 = tid + j*256;         // 0..4095 float4s
                int c = i4 >> 6, m4 = i4 & 63;
                float4 val = *(const float4*)(g + (size_t)c*12800 + m4*4);
                *(float4*)(&sx[c*256 + m4*4]) = val;
            }
        }
        __syncthreads();

        for (int h = 0; h < 2; ++h){
            const int o0 = h*32;
            float acc[32];
            #pragma unroll
            for (int j = 0; j < 32; ++j) acc[j] = bias[o0+j];
            for (int c = 0; c < 64; ++c){
                float xv = sx[c*256 + tid];
                const float* row = w + c*64 + o0;
                #pragma unroll
                for (int j = 0; j < 32; ++j) acc[j] += row[j] * xv;
            }
            float* dst = phase ? (ko + abase) : (qo + rbase);
            #pragma unroll
            for (int j = 0; j < 32; ++j)
                dst[(size_t)(o0+j)*12800 + p0 + tid] = acc[j];
        }
    }
}

// ---------------------------------------------------------------------------
// K2p: partial scores. Block = n_rel*32 + s*4 + kq (256 blocks/group).
// Each wave sums 128 K-rows; q per-lane, k rows wave-uniform (scalar loads).
__global__ __launch_bounds__(256, 2) void k2_partial(
    const float* __restrict__ qc, const float* __restrict__ kd,
    float* __restrict__ pscore, int n0)
{
    __shared__ float red[4*2500];             // 40 KB
    const int bid  = blockIdx.x;
    const int kq   = bid & 3;
    const int s    = (bid >> 2) & 7;
    const int nrel = bid >> 5;
    const int tid  = threadIdx.x;
    const int wave = __builtin_amdgcn_readfirstlane(tid >> 6);
    const int lane = tid & 63;
    const float* qf = qc + (size_t)nrel * 819200 + (size_t)s * 102400;
    const float* kf = kd + (size_t)(n0 + nrel) * 819200 + (size_t)s * 102400;

    float acc[50];
    #pragma unroll
    for (int w = 0; w < 50; ++w) acc[w] = 0.f;

    if (lane < 50){
        const int r0 = kq*512 + wave*128;
        for (int kk = r0; kk < r0 + 128; kk += 4){
            float qv[4];
            #pragma unroll
            for (int t = 0; t < 4; ++t) qv[t] = qf[(size_t)(kk+t)*50 + lane];
            #pragma unroll
            for (int t = 0; t < 4; ++t){
                const float* kr = kf + (size_t)(kk+t)*50;   // wave-uniform
                #pragma unroll
                for (int w = 0; w < 50; ++w) acc[w] += qv[t] * kr[w];
            }
        }
        #pragma unroll
        for (int w = 0; w < 50; ++w) red[wave*2500 + lane*50 + w] = acc[w];
    }
    __syncthreads();

    for (int i = tid; i < 2500; i += 256)
        pscore[(size_t)bid*2500 + i] = red[i] + red[2500+i] + red[5000+i] + red[7500+i];
}

// ---------------------------------------------------------------------------
// K2f: attn = tanh(score/2048)*alpha + gattn. Block = n_rel*8 + s.
__global__ void k2_final(const float* __restrict__ pscore,
                         const float* __restrict__ alphas, const float* __restrict__ gattn,
                         float* __restrict__ attnc)
{
    const int b = blockIdx.x;
    const int s = b & 7;
    const float inv = 1.0f / 2048.0f;
    const float alpha = alphas[s];
    for (int i = threadIdx.x; i < 2500; i += 256){
        float sum = pscore[(size_t)(b*4+0)*2500 + i] + pscore[(size_t)(b*4+1)*2500 + i]
                  + pscore[(size_t)(b*4+2)*2500 + i] + pscore[(size_t)(b*4+3)*2500 + i];
        attnc[(size_t)b*2500 + i] = tanhf(sum * inv) * alpha + gattn[i];
    }
}

// ---------------------------------------------------------------------------
// K3 v3: two chained register-tiled GEMMs. Block = (tb, nrel), 256 thr = 4 waves.
// Wave = tloc (trow = tb*4 + tloc). Lane: WL = lane>>3 (o-group), WS = lane&7
// (u/w-group). Per-lane 8x8 tile: o = 8*WL+ro; u/w = 8*WS+r (real < 50, pad
// lanes WS>=6 partially wasted, masked at P-write / store).
// LDS (dynamic, 147,968 B):
//   sx  [4][64][64]  x tile, cols 50..63 zeroed          (65,536 B)
//   sp  [4][50][64]  P, XOR-swizzled: byte ^= 16*(u>>3)  (51,200 B)
//   w2t [64][64]     W2T_s                               (16,384 B)
//   sa  [50][64]     attn_s rows, cols 50..63 zeroed     (12,800 B)
//   sovb[512]                                            ( 2,048 B)
__global__ __launch_bounds__(256, 1) void k3_out(
    const float* __restrict__ xkv, const float* __restrict__ attnc,
    const float* __restrict__ W2T, const float* __restrict__ ovb,
    const float* __restrict__ ob, float* __restrict__ out, int n0)
{
    extern __shared__ float lds[];
    float* sx   = lds;              // 16384 floats
    float* sp   = lds + 16384;      // 12800 floats
    float* sw2t = lds + 29184;      // 4096 floats
    float* sa   = lds + 33280;      // 3200 floats
    float* sovb = lds + 36480;      // 512 floats

    const int nrel = blockIdx.y;
    const int tb   = blockIdx.x;
    const int tid  = threadIdx.x;
    const int tloc = __builtin_amdgcn_readfirstlane(tid >> 6);
    const int lane = tid & 63;
    const int WL   = lane >> 3;
    const int WS   = lane & 7;
    const int trow = tb*4 + tloc;
    const size_t abase = (size_t)(n0 + nrel) * 819200;

    // ---- stage x tile: sx[tloc][a][u], 4 trows x 64 a x 50 u (f4 coalesced)
    {
        const float4* xg = (const float4*)(xkv + abase + (size_t)tb*200);
        for (int i4 = tid; i4 < 3200; i4 += 256){
            int a = i4 / 50, r = i4 - a*50;          // r: f4 within 200-float run
            float4 v = xg[(size_t)a*3200 + r];
            int g0 = r*4;
            #pragma unroll
            for (int e = 0; e < 4; ++e){
                int g = g0 + e;                      // 0..199 = (tt, u)
                int tt = g / 50, u = g - tt*50;
                sx[(tt*64 + a)*64 + u] = ((const float*)&v)[e];
            }
        }
        {   // zero pad cols 50..63 (256 threads = 4*64 rows exactly)
            int tt = tid >> 6, a = tid & 63;
            float* row = sx + (tt*64 + a)*64;
            #pragma unroll
            for (int c = 50; c < 64; ++c) row[c] = 0.f;
        }
        sovb[tid]       = ovb[tid];
        sovb[tid + 256] = ovb[tid + 256];
    }

    float acc2[8][8];
    #pragma unroll
    for (int ro = 0; ro < 8; ++ro)
        #pragma unroll
        for (int rw = 0; rw < 8; ++rw) acc2[ro][rw] = 0.f;

    const float* xw = sx + tloc*4096 + 8*WS;      // + a*64
    const float* wt = sw2t + 8*WL;                // + a*64
    char*        pb8 = (char*)(sp + tloc*3200);   // this wave's P region
    const float* aw = sa + 8*WS;                  // + u*64

    for (int s = 0; s < 8; ++s){
        __syncthreads();                          // prev GEMM2 done with sw2t/sa
        {   // stage W2T_s (linear f4 copy) + attn_s rows (pad cols zeroed)
            const float4* g4 = (const float4*)(W2T + s*4096);
            float4* d4 = (float4*)sw2t;
            #pragma unroll
            for (int it = 0; it < 4; ++it) d4[tid + it*256] = g4[tid + it*256];

            const float* ag = attnc + (size_t)(nrel*8 + s)*2500;
            for (int i = tid; i < 3200; i += 256){
                int u = i >> 6, w = i & 63;
                sa[i] = (w < 50) ? ag[u*50 + w] : 0.f;
            }
        }
        __syncthreads();

        // ---- GEMM1: P[o,u] = ovb[s,o] + sum_a W2T_s[a,o] * x[a,trow,u] ----
        float acc1[8][8];
        {
            float pbv[8];
            #pragma unroll
            for (int ro = 0; ro < 8; ++ro) pbv[ro] = sovb[s*64 + 8*WL + ro];
            #pragma unroll
            for (int ro = 0; ro < 8; ++ro)
                #pragma unroll
                for (int rm = 0; rm < 8; ++rm) acc1[ro][rm] = pbv[ro];
        }
        #pragma unroll 2
        for (int a = 0; a < 64; ++a){
            float wv[8], xv[8];
            *(float4*)&wv[0] = *(const float4*)(wt + a*64);
            *(float4*)&wv[4] = *(const float4*)(wt + a*64 + 4);
            *(float4*)&xv[0] = *(const float4*)(xw + a*64);
            *(float4*)&xv[4] = *(const float4*)(xw + a*64 + 4);
            #pragma unroll
            for (int ro = 0; ro < 8; ++ro)
                #pragma unroll
                for (int rm = 0; rm < 8; ++rm)
                    acc1[ro][rm] = fmaf(wv[ro], xv[rm], acc1[ro][rm]);
        }

        // ---- P write: sp[tloc][u][o], swizzle byte ^= 16*(u>>3) = 16*WS ----
        #pragma unroll
        for (int rm = 0; rm < 8; ++rm){
            const int u = 8*WS + rm;
            if (u < 50){
                char* row = pb8 + u*256;
                const int xo = 16*WS;
                *(float4*)(row + ((32*WL +  0) ^ xo)) =
                    make_float4(acc1[0][rm], acc1[1][rm], acc1[2][rm], acc1[3][rm]);
                *(float4*)(row + ((32*WL + 16) ^ xo)) =
                    make_float4(acc1[4][rm], acc1[5][rm], acc1[6][rm], acc1[7][rm]);
            }
        }

        // ---- GEMM2: Out[o,w] += sum_u P[o,u] * A_s[u,w] ----
        #pragma unroll 2
        for (int u = 0; u < 50; ++u){
            const int xo = 16*(u >> 3);
            float pv[8], av[8];
            *(float4*)&pv[0] = *(const float4*)(pb8 + u*256 + ((32*WL +  0) ^ xo));
            *(float4*)&pv[4] = *(const float4*)(pb8 + u*256 + ((32*WL + 16) ^ xo));
            *(float4*)&av[0] = *(const float4*)(aw + u*64);
            *(float4*)&av[4] = *(const float4*)(aw + u*64 + 4);
            #pragma unroll
            for (int ro = 0; ro < 8; ++ro)
                #pragma unroll
                for (int rw = 0; rw < 8; ++rw)
                    acc2[ro][rw] = fmaf(pv[ro], av[rw], acc2[ro][rw]);
        }
    }

    // ---- epilogue: out[o, trow, w] = acc2 + ob[o] (float2, masked w<50) ----
    #pragma unroll
    for (int ro = 0; ro < 8; ++ro){
        const int o = 8*WL + ro;
        const float b = ob[o];
        float* op = out + abase + (size_t)o*12800 + trow*50;
        #pragma unroll
        for (int j = 0; j < 4; ++j){
            const int w0 = 8*WS + 2*j;
            if (w0 <= 48)
                *(float2*)(op + w0) = make_float2(acc2[ro][2*j]   + b,
                                                  acc2[ro][2*j+1] + b);
        }
    }
}

// ---------------------------------------------------------------------------
extern "C" void kernel_launch(void* const* d_in, const int* in_sizes, int n_in,
                              void* d_out, int out_size, void* d_ws, size_t ws_size,
                              hipStream_t stream)
{
    const float* x_q    = (const float*)d_in[0];
    const float* x_kv   = (const float*)d_in[1];
    const float* q_w    = (const float*)d_in[2];
    const float* q_b    = (const float*)d_in[3];
    const float* k_w    = (const float*)d_in[4];
    const float* k_b    = (const float*)d_in[5];
    const float* v_w    = (const float*)d_in[6];
    const float* v_b    = (const float*)d_in[7];
    const float* o_w    = (const float*)d_in[8];
    const float* o_b    = (const float*)d_in[9];
    const float* alphas = (const float*)d_in[10];
    const float* gattn  = (const float*)d_in[11];
    float* out = (float*)d_out;

    // ws layout (29.6 MB):
    char* ws = (char*)d_ws;
    float* qchunk = (float*)(ws);                  // 26,214,400 B (8n q fp32)
    float* pscore = (float*)(ws + 26214400);       //  2,560,000 B
    float* attnc  = (float*)(ws + 28774400);       //    640,000 B
    float* wT     = (float*)(ws + 29414400);       //     32,768 B
    float* W2T    = (float*)(ws + 29447168);       //    131,072 B
    float* ovb    = (float*)(ws + 29578240);       //      2,048 B

    // idempotent, host-side only (legal under graph capture); no static state
    hipFuncSetAttribute((const void*)k3_out,
                        hipFuncAttributeMaxDynamicSharedMemorySize, 147968);

    k0_prep<<<146, 256, 0, stream>>>(q_w, k_w, v_w, v_b, o_w, wT, W2T, ovb);

    for (int g = 0; g < 4; ++g){
        const int n0 = g * 8;
        k1_qk<<<dim3(50, 8), 256, 0, stream>>>(x_q, x_kv, wT, q_b, k_b,
                                               qchunk, out /*k in d_out*/, n0);
        k2_partial<<<256, 256, 0, stream>>>(qchunk, (const float*)d_out, pscore, n0);
        k2_final<<<64, 256, 0, stream>>>(pscore, alphas, gattn, attnc);
        k3_out<<<dim3(64, 8), 256, 147968, stream>>>(x_kv, attnc, W2T, ovb, o_b, out, n0);
    }
}

// Round 4
// 1428.762 us; speedup vs baseline: 1.4722x; 1.1815x over previous
//
#include <hip/hip_runtime.h>

// fp32 I/O. N=32, C=64, T=256, V=50, H=8, hc=8
// plane = T*V = 12800, n-stride = 819200, score K-dim = hc*T = 2048.
// n processed in 4 groups of 8; k tensor staged in d_out (same fp32 size),
// overwritten by K3(g) only after K2(g) consumed it (stream order).
// v-projection folded into o-projection: W2T[s,a,o] = sum_c ow[o,s*64+c]*vw[c,a],
// ovb[s,o] = sum_c ow[o,s*64+c]*vb[c]  ->  K3 reads x_kv directly, no v tensor.
//
// R4 change (post-mortem of R3: k3 at 301us, VALUBusy 44%, LDS ~52%, occupancy
// 1 wave/SIMD -> latency-serialized; LDS pipe oversubscribed 192:128 per CU):
//   - Operand split by sharing class: block-private (x tile, P transpose) in
//     LDS; block-invariant (W2T, attn, ovb) read from GLOBAL via the idle
//     L1/L2 path (16KB/10.6KB per-s slices, L1-resident, same for all blocks).
//   - LDS 147.9KB -> 77.8KB (sx 2 trows, rows padded to 52; sp 4 waves)
//     => 2 blocks/CU = 2 waves/SIMD.
//   - s-loop split across wave pairs (waves 0,1: s0-3; waves 2,3: s4-7),
//     per-wave 8x8 register tile unchanged; final cross-wave acc2 reduction
//     through LDS (stride-68 rows). No barriers inside the s-loop.
//   - K2f writes attnc with row stride 52 (16B-aligned global av reads).

// ---------------------------------------------------------------------------
// K0: wT (q/k weight transpose, [c][o]) + W2T (pre-transposed [s][a][o]) + ovb
__global__ void k0_prep(const float* __restrict__ qw, const float* __restrict__ kw,
                        const float* __restrict__ vw, const float* __restrict__ vb,
                        const float* __restrict__ ow,
                        float* __restrict__ wT, float* __restrict__ W2T,
                        float* __restrict__ ovb)
{
    int i = threadIdx.x + blockIdx.x * 256;
    if (i < 4096){
        int o = i >> 6, c = i & 63;
        wT[c*64 + o]        = qw[i];
        wT[4096 + c*64 + o] = kw[i];
    } else if (i < 36864){
        int j = i - 4096;
        int s = j >> 12, o = (j >> 6) & 63, a = j & 63;
        float acc = 0.f;
        for (int c = 0; c < 64; ++c)
            acc += ow[o*512 + s*64 + c] * vw[c*64 + a];
        W2T[s*4096 + a*64 + o] = acc;            // transposed store
    } else if (i < 37376){
        int j = i - 36864;
        int s = j >> 6, o = j & 63;
        float acc = 0.f;
        for (int c = 0; c < 64; ++c)
            acc += ow[o*512 + s*64 + c] * vb[c];
        ovb[j] = acc;
    }
}

// ---------------------------------------------------------------------------
// K1: q,k projections for one n-group. Block = (pos-tile, n_rel).
// q -> qchunk (group-relative), k -> d_out (absolute).
__global__ __launch_bounds__(256, 2) void k1_qk(
    const float* __restrict__ xq, const float* __restrict__ xkv,
    const float* __restrict__ wT,
    const float* __restrict__ qb, const float* __restrict__ kb,
    float* __restrict__ qo, float* __restrict__ ko, int n0)
{
    __shared__ float sx[64*256];              // 64 KB, one tensor at a time
    const int nrel = blockIdx.y;
    const int nabs = n0 + nrel;
    const int p0   = blockIdx.x * 256;
    const int tid  = threadIdx.x;
    const size_t abase = (size_t)nabs * 819200;
    const size_t rbase = (size_t)nrel * 819200;

    for (int phase = 0; phase < 2; ++phase){
        const float* src  = phase ? xkv : xq;
        const float* bias = phase ? kb : qb;
        const float* w    = phase ? (wT + 4096) : wT;

        if (phase) __syncthreads();           // readers of prev sx done
        {   // stage 64x256 fp32 tile, float4 coalesced
            const float* g = src + abase + p0;
            #pragma unroll
            for (int j = 0; j < 16; ++j){
                int i4 = tid + j*256;         // 0..4095 float4s
                int c = i4 >> 6, m4 = i4 & 63;
                float4 val = *(const float4*)(g + (size_t)c*12800 + m4*4);
                *(float4*)(&sx[c*256 + m4*4]) = val;
            }
        }
        __syncthreads();

        for (int h = 0; h < 2; ++h){
            const int o0 = h*32;
            float acc[32];
            #pragma unroll
            for (int j = 0; j < 32; ++j) acc[j] = bias[o0+j];
            for (int c = 0; c < 64; ++c){
                float xv = sx[c*256 + tid];
                const float* row = w + c*64 + o0;
                #pragma unroll
                for (int j = 0; j < 32; ++j) acc[j] += row[j] * xv;
            }
            float* dst = phase ? (ko + abase) : (qo + rbase);
            #pragma unroll
            for (int j = 0; j < 32; ++j)
                dst[(size_t)(o0+j)*12800 + p0 + tid] = acc[j];
        }
    }
}

// ---------------------------------------------------------------------------
// K2p: partial scores. Block = n_rel*32 + s*4 + kq (256 blocks/group).
// Each wave sums 128 K-rows; q per-lane, k rows wave-uniform (scalar loads).
__global__ __launch_bounds__(256, 2) void k2_partial(
    const float* __restrict__ qc, const float* __restrict__ kd,
    float* __restrict__ pscore, int n0)
{
    __shared__ float red[4*2500];             // 40 KB
    const int bid  = blockIdx.x;
    const int kq   = bid & 3;
    const int s    = (bid >> 2) & 7;
    const int nrel = bid >> 5;
    const int tid  = threadIdx.x;
    const int wave = __builtin_amdgcn_readfirstlane(tid >> 6);
    const int lane = tid & 63;
    const float* qf = qc + (size_t)nrel * 819200 + (size_t)s * 102400;
    const float* kf = kd + (size_t)(n0 + nrel) * 819200 + (size_t)s * 102400;

    float acc[50];
    #pragma unroll
    for (int w = 0; w < 50; ++w) acc[w] = 0.f;

    if (lane < 50){
        const int r0 = kq*512 + wave*128;
        for (int kk = r0; kk < r0 + 128; kk += 4){
            float qv[4];
            #pragma unroll
            for (int t = 0; t < 4; ++t) qv[t] = qf[(size_t)(kk+t)*50 + lane];
            #pragma unroll
            for (int t = 0; t < 4; ++t){
                const float* kr = kf + (size_t)(kk+t)*50;   // wave-uniform
                #pragma unroll
                for (int w = 0; w < 50; ++w) acc[w] += qv[t] * kr[w];
            }
        }
        #pragma unroll
        for (int w = 0; w < 50; ++w) red[wave*2500 + lane*50 + w] = acc[w];
    }
    __syncthreads();

    for (int i = tid; i < 2500; i += 256)
        pscore[(size_t)bid*2500 + i] = red[i] + red[2500+i] + red[5000+i] + red[7500+i];
}

// ---------------------------------------------------------------------------
// K2f: attn = tanh(score/2048)*alpha + gattn. Block = n_rel*8 + s.
// R4: output rows padded to stride 52 (attnc[b][u][52], cols 50..51 unwritten)
// so K3's global float4 reads stay 16B-aligned.
__global__ void k2_final(const float* __restrict__ pscore,
                         const float* __restrict__ alphas, const float* __restrict__ gattn,
                         float* __restrict__ attnc)
{
    const int b = blockIdx.x;
    const int s = b & 7;
    const float inv = 1.0f / 2048.0f;
    const float alpha = alphas[s];
    for (int i = threadIdx.x; i < 2500; i += 256){
        float sum = pscore[(size_t)(b*4+0)*2500 + i] + pscore[(size_t)(b*4+1)*2500 + i]
                  + pscore[(size_t)(b*4+2)*2500 + i] + pscore[(size_t)(b*4+3)*2500 + i];
        int u = i / 50, w = i - u*50;
        attnc[(size_t)b*2600 + u*52 + w] = tanhf(sum * inv) * alpha + gattn[i];
    }
}

// ---------------------------------------------------------------------------
// K3 v4: two chained register-tiled GEMMs, s-split across wave pairs.
// Block = (tb, nrel): trows tb*2 + {0,1}. 256 thr = 4 waves.
// Wave wv: tloc = wv&1 (trow), sh = wv>>1 (s-half: s in [4*sh, 4*sh+4)).
// Lane: WL = lane>>3 (o-group), WS = lane&7 (u/w-group); per-lane 8x8 tile.
//   GEMM1: P[o,u] = ovb + W2T_s[a,o].x[a,trow,u]  (W2T, ovb from GLOBAL/L1)
//   GEMM2: acc2[o,w] += P[o,u].A_s[u,w]           (A from GLOBAL/L1, stride 52)
// LDS (dynamic, 77,824 B -> 2 blocks/CU):
//   sx [2][64][52] x tile (rows 50..51 garbage, consumed only by masked u)
//   sp [4][50][64] per-wave P, XOR-swizzled: byte ^= 16*(u>>3)
//   red (epilogue overlay at lds+0): [128][68] cross-pair acc2 reduction
__global__ __launch_bounds__(256, 2) void k3_out(
    const float* __restrict__ xkv, const float* __restrict__ attnc,
    const float* __restrict__ W2T, const float* __restrict__ ovb,
    const float* __restrict__ ob, float* __restrict__ out, int n0)
{
    extern __shared__ float lds[];
    float* sx = lds;                 // 6656 floats (2*64*52)
    float* sp = lds + 6656;          // 12800 floats (4*50*64)

    const int nrel = blockIdx.y;
    const int tb   = blockIdx.x;
    const int tid  = threadIdx.x;
    const int wv   = __builtin_amdgcn_readfirstlane(tid >> 6);
    const int lane = tid & 63;
    const int tloc = wv & 1;
    const int sh   = wv >> 1;
    const int WL   = lane >> 3;
    const int WS   = lane & 7;
    const int trow = tb*2 + tloc;
    const size_t abase = (size_t)(n0 + nrel) * 819200;

    // ---- stage x tile: sx[tt][a][u] (stride 52), 2 trows x 64 a x 50 u ----
    {
        const float4* xg = (const float4*)(xkv + abase);
        for (int i4 = tid; i4 < 1600; i4 += 256){
            int a = i4 / 25, j = i4 - a*25;          // 25 f4 = 100 floats per a
            float4 v = xg[(size_t)a*3200 + tb*25 + j];
            int g0 = j*4;
            #pragma unroll
            for (int e = 0; e < 4; ++e){
                int g = g0 + e;                      // 0..99 = (tt, u)
                int tt = (g >= 50) ? 1 : 0;
                sx[tt*3328 + a*52 + (g - tt*50)] = ((const float*)&v)[e];
            }
        }
    }
    __syncthreads();

    float acc2[8][8];
    #pragma unroll
    for (int ro = 0; ro < 8; ++ro)
        #pragma unroll
        for (int rw = 0; rw < 8; ++rw) acc2[ro][rw] = 0.f;

    const float* xw  = sx + tloc*3328 + 8*WS;     // + a*52 (LDS)
    char*        pb8 = (char*)(sp + wv*3200);     // wave-private P
    const float* agb = attnc + (size_t)(nrel*8)*2600 + 8*WS;   // + s*2600 + u*52

    for (int si = 0; si < 4; ++si){
        const int s = sh*4 + si;

        // ---- GEMM1: P[o,u] = ovb[s,o] + sum_a W2T_s[a,o] * x[a,trow,u] ----
        float acc1[8][8];
        {
            float pbv[8];
            *(float4*)&pbv[0] = *(const float4*)(ovb + s*64 + 8*WL);
            *(float4*)&pbv[4] = *(const float4*)(ovb + s*64 + 8*WL + 4);
            #pragma unroll
            for (int ro = 0; ro < 8; ++ro)
                #pragma unroll
                for (int rm = 0; rm < 8; ++rm) acc1[ro][rm] = pbv[ro];
        }
        const float* wS = W2T + s*4096 + 8*WL;    // global, L1-resident slice
        #pragma unroll 2
        for (int a = 0; a < 64; ++a){
            float wvx[8], xv[8];
            *(float4*)&wvx[0] = *(const float4*)(wS + a*64);      // global f4
            *(float4*)&wvx[4] = *(const float4*)(wS + a*64 + 4);  // global f4
            *(float4*)&xv[0]  = *(const float4*)(xw + a*52);      // LDS b128
            *(float4*)&xv[4]  = *(const float4*)(xw + a*52 + 4);  // LDS b128
            #pragma unroll
            for (int ro = 0; ro < 8; ++ro)
                #pragma unroll
                for (int rm = 0; rm < 8; ++rm)
                    acc1[ro][rm] = fmaf(wvx[ro], xv[rm], acc1[ro][rm]);
        }

        // ---- P write: sp[wv][u][o], swizzle byte ^= 16*(u>>3) = 16*WS ----
        #pragma unroll
        for (int rm = 0; rm < 8; ++rm){
            const int u = 8*WS + rm;
            if (u < 50){
                char* row = pb8 + u*256;
                const int xo = 16*WS;
                *(float4*)(row + ((32*WL +  0) ^ xo)) =
                    make_float4(acc1[0][rm], acc1[1][rm], acc1[2][rm], acc1[3][rm]);
                *(float4*)(row + ((32*WL + 16) ^ xo)) =
                    make_float4(acc1[4][rm], acc1[5][rm], acc1[6][rm], acc1[7][rm]);
            }
        }

        // ---- GEMM2: acc2[o,w] += sum_u P[o,u] * A_s[u,w] (A global/L1) ----
        const float* aS = agb + (size_t)s*2600;
        #pragma unroll 2
        for (int u = 0; u < 50; ++u){
            const int xo = 16*(u >> 3);
            float pv[8], av[8];
            *(float4*)&pv[0] = *(const float4*)(pb8 + u*256 + ((32*WL +  0) ^ xo));
            *(float4*)&pv[4] = *(const float4*)(pb8 + u*256 + ((32*WL + 16) ^ xo));
            *(float4*)&av[0] = *(const float4*)(aS + u*52);       // global f4
            *(float4*)&av[4] = *(const float4*)(aS + u*52 + 4);   // global f4
            #pragma unroll
            for (int ro = 0; ro < 8; ++ro)
                #pragma unroll
                for (int rw = 0; rw < 8; ++rw)
                    acc2[ro][rw] = fmaf(pv[ro], av[rw], acc2[ro][rw]);
        }
    }

    // ---- cross-pair (s-half) reduction through LDS overlay, then store ----
    __syncthreads();                              // sx/sp dead now
    float* red = lds;                             // [128][68] floats
    if (sh == 1){
        float* r = red + (tloc*64 + lane)*68;
        #pragma unroll
        for (int j = 0; j < 16; ++j){
            const int ro = (4*j) >> 3, rw = (4*j) & 7;
            *(float4*)(r + 4*j) = make_float4(acc2[ro][rw],   acc2[ro][rw+1],
                                              acc2[ro][rw+2], acc2[ro][rw+3]);
        }
    }
    __syncthreads();
    if (sh == 0){
        const float* r = red + (tloc*64 + lane)*68;
        #pragma unroll
        for (int j = 0; j < 16; ++j){
            const int ro = (4*j) >> 3, rw = (4*j) & 7;
            float4 rv = *(const float4*)(r + 4*j);
            acc2[ro][rw]   += rv.x;  acc2[ro][rw+1] += rv.y;
            acc2[ro][rw+2] += rv.z;  acc2[ro][rw+3] += rv.w;
        }
        #pragma unroll
        for (int ro = 0; ro < 8; ++ro){
            const int o = 8*WL + ro;
            const float b = ob[o];
            float* op = out + abase + (size_t)o*12800 + trow*50;
            #pragma unroll
            for (int j = 0; j < 4; ++j){
                const int w0 = 8*WS + 2*j;
                if (w0 <= 48)
                    *(float2*)(op + w0) = make_float2(acc2[ro][2*j]   + b,
                                                      acc2[ro][2*j+1] + b);
            }
        }
    }
}

// ---------------------------------------------------------------------------
extern "C" void kernel_launch(void* const* d_in, const int* in_sizes, int n_in,
                              void* d_out, int out_size, void* d_ws, size_t ws_size,
                              hipStream_t stream)
{
    const float* x_q    = (const float*)d_in[0];
    const float* x_kv   = (const float*)d_in[1];
    const float* q_w    = (const float*)d_in[2];
    const float* q_b    = (const float*)d_in[3];
    const float* k_w    = (const float*)d_in[4];
    const float* k_b    = (const float*)d_in[5];
    const float* v_w    = (const float*)d_in[6];
    const float* v_b    = (const float*)d_in[7];
    const float* o_w    = (const float*)d_in[8];
    const float* o_b    = (const float*)d_in[9];
    const float* alphas = (const float*)d_in[10];
    const float* gattn  = (const float*)d_in[11];
    float* out = (float*)d_out;

    // ws layout (29.6 MB):
    char* ws = (char*)d_ws;
    float* qchunk = (float*)(ws);                  // 26,214,400 B (8n q fp32)
    float* pscore = (float*)(ws + 26214400);       //  2,560,000 B
    float* attnc  = (float*)(ws + 28774400);       //    665,600 B (stride-52 rows)
    float* wT     = (float*)(ws + 29440000);       //     32,768 B
    float* W2T    = (float*)(ws + 29472768);       //    131,072 B
    float* ovb    = (float*)(ws + 29603840);       //      2,048 B

    // idempotent, host-side only (legal under graph capture); no static state
    hipFuncSetAttribute((const void*)k3_out,
                        hipFuncAttributeMaxDynamicSharedMemorySize, 77824);

    k0_prep<<<146, 256, 0, stream>>>(q_w, k_w, v_w, v_b, o_w, wT, W2T, ovb);

    for (int g = 0; g < 4; ++g){
        const int n0 = g * 8;
        k1_qk<<<dim3(50, 8), 256, 0, stream>>>(x_q, x_kv, wT, q_b, k_b,
                                               qchunk, out /*k in d_out*/, n0);
        k2_partial<<<256, 256, 0, stream>>>(qchunk, (const float*)d_out, pscore, n0);
        k2_final<<<64, 256, 0, stream>>>(pscore, alphas, gattn, attnc);
        k3_out<<<dim3(128, 8), 256, 77824, stream>>>(x_kv, attnc, W2T, ovb, o_b, out, n0);
    }
}